// Round 11
// baseline (15.696 us; speedup 1.0000x reference)
//
#include <hip/hip_runtime.h>
#include <math.h>

#define EPSF 1e-8f

constexpr int B = 512;
constexpr int F = 256;

using frag_ab = __attribute__((ext_vector_type(8))) short;   // 8 bf16
using f32x4   = __attribute__((ext_vector_type(4))) float;

__device__ __forceinline__ unsigned short f2bf(float f) {
    unsigned int u = __float_as_uint(f);
    unsigned int r = (u + 0x7fffu + ((u >> 16) & 1u)) >> 16;   // RNE
    return (unsigned short)r;
}

// ---- K1: bf16 Gram tile GEMM, 1 wave per 16x16 tile, 1024 blocks ----------
// R10 verbatim: fp32->bf16 convert fused in staging; diagonal tiles emit
// invs[row] from the Gram diagonal.
__global__ __launch_bounds__(64) void gram_mfma(
    const float* __restrict__ feats, float* __restrict__ gram,
    float* __restrict__ invs)
{
    const int bid = blockIdx.x;
    const int it = bid >> 5, jt = bid & 31;      // 32x32 grid of 16x16 tiles
    const int l = threadIdx.x;

    __shared__ __align__(16) unsigned char Abf[16 * 512];   // 16 rows x 512 B
    __shared__ __align__(16) unsigned char Bbf[16 * 512];

    const float4* Ag = (const float4*)(feats + (size_t)(it * 16) * F);
    const float4* Bg = (const float4*)(feats + (size_t)(jt * 16) * F);

    #pragma unroll
    for (int m = 0; m < 16; ++m) {               // row m, lane l = float4 #l
        const int swz = ((l >> 1) ^ (m & 7)) * 16 + (l & 1) * 8;
        float4 a = Ag[m * 64 + l];
        ushort4 ha = { f2bf(a.x), f2bf(a.y), f2bf(a.z), f2bf(a.w) };
        *(ushort4*)(Abf + m * 512 + swz) = ha;
        float4 b = Bg[m * 64 + l];
        ushort4 hb = { f2bf(b.x), f2bf(b.y), f2bf(b.z), f2bf(b.w) };
        *(ushort4*)(Bbf + m * 512 + swz) = hb;
    }
    // single wave: compiler orders ds_write -> ds_read via lgkmcnt

    const int row_f = l & 15;
    const int kg    = l >> 4;
    f32x4 acc = {0.f, 0.f, 0.f, 0.f};
    #pragma unroll
    for (int kc = 0; kc < 8; ++kc) {
        int cc = (kc * 4 + kg) ^ (row_f & 7);
        frag_ab a = *(const frag_ab*)(Abf + row_f * 512 + cc * 16);
        frag_ab b = *(const frag_ab*)(Bbf + row_f * 512 + cc * 16);
        acc = __builtin_amdgcn_mfma_f32_16x16x32_bf16(a, b, acc, 0, 0, 0);
    }
    // C layout (verified): col = lane&15, row = (lane>>4)*4 + j
    const int col = l & 15;
    #pragma unroll
    for (int j = 0; j < 4; ++j) {
        int row = kg * 4 + j;
        float v = acc[j];
        gram[(size_t)(it * 16 + row) * B + jt * 16 + col] = v;
        if (it == jt && col == row)              // gram[r][r] -> inverse norm
            invs[it * 16 + row] = 1.f / fmaxf(sqrtf(v + EPSF), EPSF);
    }
}

// ---- K2: one WAVE per row, zero barriers ----------------------------------
// Lane l owns j = q*64+l for q=0..7. Pattern margins (ids in {0,1}^4),
// running-ballot compaction into per-block vals[], 8-stream hinge loop.
__global__ __launch_bounds__(64) void row_wave(
    const int* __restrict__ ids, const float* __restrict__ gram,
    const float* __restrict__ invs,
    float* __restrict__ rowloss, int* __restrict__ rowvalid)
{
    const int i = blockIdx.x;
    const int l = threadIdx.x;

    __shared__ float vals[B];                    // 2 KB

    const int4 idi = ((const int4*)ids)[i];      // wave-uniform
    const int pi = (idi.x & 1) | ((idi.y & 1) << 1)
                 | ((idi.z & 1) << 2) | ((idi.w & 1) << 3);
    const float invi = invs[i];                  // wave-uniform

    float cosv[8];
    int   pj[8];
    #pragma unroll
    for (int q = 0; q < 8; ++q) {
        const int j = q * 64 + l;
        int4 v = ((const int4*)ids)[j];          // coalesced
        pj[q] = (v.x & 1) | ((v.y & 1) << 1) | ((v.z & 1) << 2) | ((v.w & 1) << 3);
        cosv[q] = gram[(size_t)i * B + j] * invi * invs[j];   // coalesced
    }

    // running-ballot compaction of the sim set (deterministic fixed order)
    const unsigned long long lmask = (1ull << l) - 1ull;
    int off = 0;
    #pragma unroll
    for (int q = 0; q < 8; ++q) {
        const int j = q * 64 + l;
        const bool sim = (pj[q] == pi) && (j != i);
        const unsigned long long m = __ballot(sim);
        if (sim) vals[off + (int)__popcll(m & lmask)] = cosv[q];
        off += (int)__popcll(m);
    }
    const int ns = off;

    // negatives: sentinel for sim slots (fmax(0, -1e30 - a) == 0)
    float b[8];
    #pragma unroll
    for (int q = 0; q < 8; ++q)
        b[q] = (pj[q] != pi) ? 0.15f * (float)__popc(pj[q] ^ pi) + cosv[q]
                             : -1e30f;

    // 8 independent accumulator streams; vals reads pipeline (indep addrs)
    float sa[8] = {0.f, 0.f, 0.f, 0.f, 0.f, 0.f, 0.f, 0.f};
    for (int t = 0; t < ns; ++t) {
        const float a = vals[t];                 // broadcast LDS read
        #pragma unroll
        for (int q = 0; q < 8; ++q) sa[q] += fmaxf(0.f, b[q] - a);
    }
    float s = ((sa[0] + sa[1]) + (sa[2] + sa[3]))
            + ((sa[4] + sa[5]) + (sa[6] + sa[7]));
    #pragma unroll
    for (int o = 32; o > 0; o >>= 1) s += __shfl_down(s, o);

    if (l == 0) {
        const int nd = (B - 1) - ns;             // j != i is sim xor dif
        const long cnt = (long)ns * (long)nd;
        rowloss[i]  = (cnt > 0) ? s / (float)cnt : 0.f;
        rowvalid[i] = (cnt > 0) ? 1 : 0;
    }
}

// ---- K3: final mean over valid rows (verbatim) ----------------------------
__global__ __launch_bounds__(256) void finalize_kernel(
    const float* __restrict__ rowloss, const int* __restrict__ rowvalid,
    float* __restrict__ out)
{
    const int tid  = threadIdx.x;
    const int lane = tid & 63;
    const int wid  = tid >> 6;
    __shared__ float sb[4], vb[4];

    float s = rowloss[tid] + rowloss[tid + 256];
    float v = (float)(rowvalid[tid] + rowvalid[tid + 256]);
    #pragma unroll
    for (int o = 32; o > 0; o >>= 1) {
        s += __shfl_down(s, o);
        v += __shfl_down(v, o);
    }
    if (lane == 0) { sb[wid] = s; vb[wid] = v; }
    __syncthreads();
    if (tid == 0) {
        float ts = sb[0] + sb[1] + sb[2] + sb[3];
        float tv = vb[0] + vb[1] + vb[2] + vb[3];
        out[0] = ts / fmaxf(tv, 1.f);
    }
}

extern "C" void kernel_launch(void* const* d_in, const int* in_sizes, int n_in,
                              void* d_out, int out_size, void* d_ws, size_t ws_size,
                              hipStream_t stream) {
    const int*   ids   = (const int*)d_in[0];
    const float* feats = (const float*)d_in[1];
    float* out = (float*)d_out;

    char* ws = (char*)d_ws;
    float* gram     = (float*)ws;                           // 1 MB
    float* invs     = (float*)(ws + (1u << 20));            // 2 KB
    float* rowloss  = (float*)(ws + (1u << 20) + 2048);     // 2 KB
    int*   rowvalid = (int*)(ws + (1u << 20) + 4096);       // 2 KB

    hipLaunchKernelGGL(gram_mfma, dim3(32 * 32), dim3(64), 0, stream,
                       feats, gram, invs);
    hipLaunchKernelGGL(row_wave, dim3(B), dim3(64), 0, stream,
                       ids, gram, invs, rowloss, rowvalid);
    hipLaunchKernelGGL(finalize_kernel, dim3(1), dim3(256), 0, stream,
                       rowloss, rowvalid, out);
}